// Round 1
// baseline (800.998 us; speedup 1.0000x reference)
//
#include <hip/hip_runtime.h>

// RecursiveEncoder on MI355X.
// Sizes: B=16, H=256, S=16, C=5, L=6, N_LEAF=5^6=15625, N_INT=3906.
// Strategy:
//   prep:   W_node (3,1280,256) fp32 -> Wt bf16 [3][256][1280] (n-major, K contiguous); zero counters
//   leaf:   feats6[row][h] = relu(box@W_box+b_box)+relu(sem@W_sem+b_sem), bf16 out
//   bucket: per (level,type) lists of (out_row, a_row). A-row of a node is CONTIGUOUS
//           (5 consecutive child rows of feats_{l+1}).
//   level:  bucketed bf16 MFMA GEMM M=count,K=1280,N=256, 64-row tiles, fused epilogue
//   head:   fp32 MLP + reparam + kld -> out (16,512) fp32
// Workspace need ~164 MB (f6 bf16 = 128 MB dominates).

#define B_ 16
#define H_ 256
#define NLEAF 15625
#define NINT 3906

typedef __bf16 bf16_t;
typedef bf16_t bf16x8 __attribute__((ext_vector_type(8)));
typedef float f32x4 __attribute__((ext_vector_type(4)));

__global__ __launch_bounds__(256) void prep_kernel(const float* __restrict__ W_node,
                                                   bf16_t* __restrict__ Wt,
                                                   int* __restrict__ counters) {
  int idx = blockIdx.x * 256 + threadIdx.x;
  if (idx < 18) counters[idx] = 0;
  if (idx >= 3 * 1280 * 256) return;
  int t = idx / (1280 * 256);
  int rem = idx - t * 1280 * 256;
  int k = rem >> 8;
  int h = rem & 255;
  Wt[((size_t)(t * 256 + h)) * 1280 + k] = (bf16_t)W_node[idx];
}

__global__ __launch_bounds__(256) void leaf_kernel(
    const float* __restrict__ leaf_box, const float* __restrict__ leaf_sem,
    const float* __restrict__ W_box, const float* __restrict__ b_box,
    const float* __restrict__ W_sem, const float* __restrict__ b_sem,
    bf16_t* __restrict__ f6) {
  int h = threadIdx.x;
  float wb[4], ws[16];
#pragma unroll
  for (int j = 0; j < 4; ++j) wb[j] = W_box[j * H_ + h];
#pragma unroll
  for (int j = 0; j < 16; ++j) ws[j] = W_sem[j * H_ + h];
  float bb = b_box[h], bs = b_sem[h];
  const int ROWS = B_ * NLEAF;
  for (int row = blockIdx.x; row < ROWS; row += gridDim.x) {
    float4 bx = *(const float4*)(leaf_box + (size_t)row * 4);
    float s1 = fmaf(wb[0], bx.x, fmaf(wb[1], bx.y, fmaf(wb[2], bx.z, fmaf(wb[3], bx.w, bb))));
    const float4* sp = (const float4*)(leaf_sem + (size_t)row * 16);
    float s2 = bs;
#pragma unroll
    for (int j = 0; j < 4; ++j) {
      float4 sv = sp[j];
      s2 = fmaf(ws[4 * j + 0], sv.x, s2);
      s2 = fmaf(ws[4 * j + 1], sv.y, s2);
      s2 = fmaf(ws[4 * j + 2], sv.z, s2);
      s2 = fmaf(ws[4 * j + 3], sv.w, s2);
    }
    float v = fmaxf(s1, 0.f) + fmaxf(s2, 0.f);
    f6[(size_t)row * H_ + h] = (bf16_t)v;
  }
}

__global__ __launch_bounds__(256) void bucket_kernel(const int* __restrict__ node_type,
                                                     int* __restrict__ counters,
                                                     int2* __restrict__ buckets) {
  int idx = blockIdx.x * 256 + threadIdx.x;
  if (idx >= B_ * NINT) return;
  int b = idx / NINT;
  int j = idx - b * NINT;
  int l, off;
  if (j >= 781)      { l = 5; off = 781; }
  else if (j >= 156) { l = 4; off = 156; }
  else if (j >= 31)  { l = 3; off = 31; }
  else if (j >= 6)   { l = 2; off = 6; }
  else if (j >= 1)   { l = 1; off = 1; }
  else               { l = 0; off = 0; }
  const int n_tab[6]    = {1, 5, 25, 125, 625, 3125};
  const int nn_tab[6]   = {5, 25, 125, 625, 3125, 15625};
  const int base_tab[6] = {0, 48, 288, 1488, 7488, 37488};
  int n_l = n_tab[l], nn = nn_tab[l];
  int t = node_type[idx];  // 0..2
  int i = j - off;
  int pos = atomicAdd(&counters[l * 3 + t], 1);
  int2 e;
  e.x = b * n_l + i;        // output row in feats_l
  e.y = b * nn + 5 * i;     // first child row in feats_{l+1} (5 contiguous rows)
  buckets[base_tab[l] + t * (B_ * n_l) + pos] = e;
}

// One block: 64 rows x 256 cols, K=1280 in 40 steps of 32. 4 waves, each 16 rows.
__global__ __launch_bounds__(256) void level_kernel(
    const bf16_t* __restrict__ src, bf16_t* __restrict__ dst,
    const int2* __restrict__ bucket, const int* __restrict__ counters,
    const bf16_t* __restrict__ Wt, const float* __restrict__ b_node,
    const float* __restrict__ ibox, const float* __restrict__ W_box,
    const float* __restrict__ b_box, int n_l, int off_l, int cap) {
  const int t = blockIdx.y;
  const int cnt = counters[t];
  const int tile0 = blockIdx.x * 64;
  if (tile0 >= cnt) return;
  const int2* rd = bucket + (size_t)t * cap;

  // +8 pad (row stride 80B, 16B-aligned) -> <=2-way bank aliasing on b128 reads (free)
  __shared__ __align__(16) bf16_t Asm[64][40];
  __shared__ __align__(16) bf16_t Bsm[256][40];

  const int tid = threadIdx.x;
  const int lane = tid & 63;
  const int wave = tid >> 6;
  const int quad = lane >> 4;
  const int l15 = lane & 15;

  // A staging assignment: thread -> (row, 16B chunk)
  const int ar = tid >> 2;
  const int ac = tid & 3;
  int aidx = tile0 + ar;
  if (aidx >= cnt) aidx = cnt - 1;  // clamp: duplicate row, never stored
  const size_t a_base = (size_t)rd[aidx].y * H_ + ac * 8;

  const bf16_t* wsrc = Wt + (size_t)t * 256 * 1280;

  f32x4 acc[16];
#pragma unroll
  for (int c = 0; c < 16; ++c) acc[c] = (f32x4){0.f, 0.f, 0.f, 0.f};

  for (int ks = 0; ks < 40; ++ks) {
    int4 av = *(const int4*)(src + a_base + ks * 32);
    *(int4*)(&Asm[ar][ac * 8]) = av;
#pragma unroll
    for (int it = 0; it < 4; ++it) {
      int q = tid + it * 256;
      int n = q >> 2, ch = q & 3;
      int4 bv = *(const int4*)(wsrc + (size_t)n * 1280 + ks * 32 + ch * 8);
      *(int4*)(&Bsm[n][ch * 8]) = bv;
    }
    __syncthreads();
    // A frag: A[m=lane&15][k=quad*8+j]; B frag: B[k=quad*8+j][n=lane&15] (Bsm is n-major)
    bf16x8 af = *(const bf16x8*)(&Asm[wave * 16 + l15][quad * 8]);
#pragma unroll
    for (int c = 0; c < 16; ++c) {
      bf16x8 bfr = *(const bf16x8*)(&Bsm[c * 16 + l15][quad * 8]);
      acc[c] = __builtin_amdgcn_mfma_f32_16x16x32_bf16(af, bfr, acc[c], 0, 0, 0);
    }
    __syncthreads();
  }

  // Epilogue. C/D layout: col = lane&15, row = quad*4 + reg.
  int orow[4]; float4 bxv[4]; int valid[4];
#pragma unroll
  for (int r = 0; r < 4; ++r) {
    int lrow = wave * 16 + quad * 4 + r;
    int gidx = tile0 + lrow;
    valid[r] = (gidx < cnt);
    int ic = valid[r] ? gidx : (cnt - 1);
    int orw = rd[ic].x;
    orow[r] = orw;
    int b = orw / n_l;
    int i = orw - b * n_l;
    bxv[r] = *(const float4*)(ibox + ((size_t)b * NINT + off_l + i) * 4);
  }
#pragma unroll
  for (int c = 0; c < 16; ++c) {
    int col = c * 16 + l15;
    float wb0 = W_box[col], wb1 = W_box[H_ + col], wb2 = W_box[2 * H_ + col],
          wb3 = W_box[3 * H_ + col];
    float bb = b_box[col];
    float bn = b_node[t * H_ + col];
#pragma unroll
    for (int r = 0; r < 4; ++r) {
      if (!valid[r]) continue;
      float y = fmaxf(acc[c][r] + bn, 0.f);
      float be = fmaf(wb0, bxv[r].x, fmaf(wb1, bxv[r].y, fmaf(wb2, bxv[r].z, fmaf(wb3, bxv[r].w, bb))));
      be = fmaxf(be, 0.f);
      dst[(size_t)orow[r] * H_ + col] = (bf16_t)(y + be);
    }
  }
}

__global__ __launch_bounds__(256) void head_kernel(
    const bf16_t* __restrict__ f0, const float* __restrict__ eps,
    const float* __restrict__ W1, const float* __restrict__ b1,
    const float* __restrict__ Wmu, const float* __restrict__ bmu,
    const float* __restrict__ Wvar, const float* __restrict__ bvar,
    float* __restrict__ out) {
  __shared__ float root[256];
  __shared__ float enc[256];
  int b = blockIdx.x, h = threadIdx.x;
  root[h] = (float)f0[b * H_ + h];
  __syncthreads();
  float a = b1[h];
  for (int k = 0; k < 256; ++k) a = fmaf(root[k], W1[k * H_ + h], a);
  enc[h] = fmaxf(a, 0.f);
  __syncthreads();
  float m = bmu[h], lv = bvar[h];
  for (int k = 0; k < 256; ++k) {
    float e = enc[k];
    m = fmaf(e, Wmu[k * H_ + h], m);
    lv = fmaf(e, Wvar[k * H_ + h], lv);
  }
  float stdv = expf(0.5f * lv);
  float kld = 1.f + lv - m * m - expf(lv);
  out[b * 512 + h] = eps[b * H_ + h] * stdv + m;
  out[b * 512 + 256 + h] = kld;
}

extern "C" void kernel_launch(void* const* d_in, const int* in_sizes, int n_in,
                              void* d_out, int out_size, void* d_ws, size_t ws_size,
                              hipStream_t stream) {
  const float* leaf_box     = (const float*)d_in[0];
  const float* leaf_sem     = (const float*)d_in[1];
  const float* internal_box = (const float*)d_in[2];
  const int*   node_type    = (const int*)d_in[3];
  const float* eps          = (const float*)d_in[4];
  const float* W_box        = (const float*)d_in[5];
  const float* b_box        = (const float*)d_in[6];
  const float* W_sem        = (const float*)d_in[7];
  const float* b_sem        = (const float*)d_in[8];
  const float* W_node       = (const float*)d_in[9];
  const float* b_node       = (const float*)d_in[10];
  const float* W1           = (const float*)d_in[11];
  const float* b1           = (const float*)d_in[12];
  const float* Wmu          = (const float*)d_in[13];
  const float* bmu          = (const float*)d_in[14];
  const float* Wvar         = (const float*)d_in[15];
  const float* bvar         = (const float*)d_in[16];
  float* out = (float*)d_out;

  char* p = (char*)d_ws;
  auto alloc = [&](size_t bytes) {
    char* r = p;
    p += (bytes + 255) & ~(size_t)255;
    return r;
  };
  bf16_t* Wt = (bf16_t*)alloc((size_t)3 * 256 * 1280 * 2);
  const int n_tab[7] = {1, 5, 25, 125, 625, 3125, 15625};
  bf16_t* f[7];
  for (int l = 0; l <= 6; ++l) f[l] = (bf16_t*)alloc((size_t)B_ * n_tab[l] * H_ * 2);
  int* counters = (int*)alloc(18 * 4);
  int2* buckets = (int2*)alloc((size_t)187488 * 8);

  hipLaunchKernelGGL(prep_kernel, dim3(3840), dim3(256), 0, stream, W_node, Wt, counters);
  hipLaunchKernelGGL(leaf_kernel, dim3(4096), dim3(256), 0, stream,
                     leaf_box, leaf_sem, W_box, b_box, W_sem, b_sem, f[6]);
  hipLaunchKernelGGL(bucket_kernel, dim3((B_ * NINT + 255) / 256), dim3(256), 0, stream,
                     node_type, counters, buckets);

  const int lvl_base[6] = {0, 48, 288, 1488, 7488, 37488};
  const int off_tab[6]  = {0, 1, 6, 31, 156, 781};
  for (int l = 5; l >= 0; --l) {
    int cap = B_ * n_tab[l];
    int tiles = (cap + 63) / 64;
    hipLaunchKernelGGL(level_kernel, dim3(tiles, 3), dim3(256), 0, stream,
                       f[l + 1], f[l], buckets + lvl_base[l], counters + l * 3,
                       Wt, b_node, internal_box, W_box, b_box,
                       n_tab[l], off_tab[l], cap);
  }
  hipLaunchKernelGGL(head_kernel, dim3(16), dim3(256), 0, stream,
                     f[0], eps, W1, b1, Wmu, bmu, Wvar, bvar, out);
}

// Round 2
// 435.008 us; speedup vs baseline: 1.8413x; 1.8413x over previous
//
#include <hip/hip_runtime.h>

// RecursiveEncoder on MI355X. B=16, H=256, S=16, C=5, L=6, N_LEAF=15625, N_INT=3906.
// R2: (1) bucket_kernel LDS-aggregated atomics (was 290us of same-address contention);
//     (2) level_kernel -> m97-style 128x128 tile, global_load_lds width-16 staging,
//         4 waves x (4x4 16x16x32 bf16 MFMA), unpadded 64B LDS rows (conflict-free).

#define B_ 16
#define H_ 256
#define NLEAF 15625
#define NINT 3906

typedef __bf16 bf16_t;
typedef bf16_t bf16x8 __attribute__((ext_vector_type(8)));
typedef float f32x4 __attribute__((ext_vector_type(4)));

__device__ __forceinline__ void gl2lds16(const bf16_t* g, bf16_t* l) {
  __builtin_amdgcn_global_load_lds((const __attribute__((address_space(1))) void*)g,
                                   (__attribute__((address_space(3))) void*)l,
                                   16, 0, 0);
}

__global__ __launch_bounds__(256) void prep_kernel(const float* __restrict__ W_node,
                                                   bf16_t* __restrict__ Wt,
                                                   int* __restrict__ counters) {
  int idx = blockIdx.x * 256 + threadIdx.x;
  if (idx < 18) counters[idx] = 0;
  if (idx >= 3 * 1280 * 256) return;
  int t = idx / (1280 * 256);
  int rem = idx - t * 1280 * 256;
  int k = rem >> 8;
  int h = rem & 255;
  Wt[((size_t)(t * 256 + h)) * 1280 + k] = (bf16_t)W_node[idx];
}

__global__ __launch_bounds__(256) void leaf_kernel(
    const float* __restrict__ leaf_box, const float* __restrict__ leaf_sem,
    const float* __restrict__ W_box, const float* __restrict__ b_box,
    const float* __restrict__ W_sem, const float* __restrict__ b_sem,
    bf16_t* __restrict__ f6) {
  int h = threadIdx.x;
  float wb[4], ws[16];
#pragma unroll
  for (int j = 0; j < 4; ++j) wb[j] = W_box[j * H_ + h];
#pragma unroll
  for (int j = 0; j < 16; ++j) ws[j] = W_sem[j * H_ + h];
  float bb = b_box[h], bs = b_sem[h];
  const int ROWS = B_ * NLEAF;
  for (int row = blockIdx.x; row < ROWS; row += gridDim.x) {
    float4 bx = *(const float4*)(leaf_box + (size_t)row * 4);
    float s1 = fmaf(wb[0], bx.x, fmaf(wb[1], bx.y, fmaf(wb[2], bx.z, fmaf(wb[3], bx.w, bb))));
    const float4* sp = (const float4*)(leaf_sem + (size_t)row * 16);
    float s2 = bs;
#pragma unroll
    for (int j = 0; j < 4; ++j) {
      float4 sv = sp[j];
      s2 = fmaf(ws[4 * j + 0], sv.x, s2);
      s2 = fmaf(ws[4 * j + 1], sv.y, s2);
      s2 = fmaf(ws[4 * j + 2], sv.z, s2);
      s2 = fmaf(ws[4 * j + 3], sv.w, s2);
    }
    float v = fmaxf(s1, 0.f) + fmaxf(s2, 0.f);
    f6[(size_t)row * H_ + h] = (bf16_t)v;
  }
}

// LDS-aggregated bucketing: 256 LDS atomics/block -> <=18 global atomics/block.
__global__ __launch_bounds__(256) void bucket_kernel(const int* __restrict__ node_type,
                                                     int* __restrict__ counters,
                                                     int2* __restrict__ buckets) {
  __shared__ int lcnt[18];
  __shared__ int lbase[18];
  const int tid = threadIdx.x;
  if (tid < 18) lcnt[tid] = 0;
  __syncthreads();

  int idx = blockIdx.x * 256 + tid;
  bool active = idx < B_ * NINT;
  int l = 0, t = 0, key = 0, mypos = 0;
  int2 e;
  int base = 0, nl_cap = 0;
  if (active) {
    int b = idx / NINT;
    int j = idx - b * NINT;
    int off;
    if (j >= 781)      { l = 5; off = 781; }
    else if (j >= 156) { l = 4; off = 156; }
    else if (j >= 31)  { l = 3; off = 31; }
    else if (j >= 6)   { l = 2; off = 6; }
    else if (j >= 1)   { l = 1; off = 1; }
    else               { l = 0; off = 0; }
    const int n_tab[6]    = {1, 5, 25, 125, 625, 3125};
    const int nn_tab[6]   = {5, 25, 125, 625, 3125, 15625};
    const int base_tab[6] = {0, 48, 288, 1488, 7488, 37488};
    int n_l = n_tab[l], nn = nn_tab[l];
    t = node_type[idx];
    int i = j - off;
    e.x = b * n_l + i;
    e.y = b * nn + 5 * i;
    base = base_tab[l];
    nl_cap = B_ * n_l;
    key = l * 3 + t;
    mypos = atomicAdd(&lcnt[key], 1);
  }
  __syncthreads();
  if (tid < 18) {
    int c = lcnt[tid];
    lbase[tid] = c ? atomicAdd(&counters[tid], c) : 0;
  }
  __syncthreads();
  if (active) {
    int pos = lbase[key] + mypos;
    buckets[base + t * nl_cap + pos] = e;
  }
}

// 128x128 tile (blockIdx.z picks N-half of 256), K=1280 in 40 steps of 32.
// 4 waves (2x2), each wave 64x64 via 4x4 grid of 16x16x32 MFMAs.
__global__ __launch_bounds__(256) void level_kernel(
    const bf16_t* __restrict__ src, bf16_t* __restrict__ dst,
    const int2* __restrict__ bucket, const int* __restrict__ counters,
    const bf16_t* __restrict__ Wt, const float* __restrict__ b_node,
    const float* __restrict__ ibox, const float* __restrict__ W_box,
    const float* __restrict__ b_box, int n_l, int off_l, int cap) {
  const int t = blockIdx.y;
  const int cnt = counters[t];
  const int tile0 = blockIdx.x * 128;
  if (tile0 >= cnt) return;
  const int nblk = blockIdx.z;  // cols [nblk*128, nblk*128+128)
  const int2* rd = bucket + (size_t)t * cap;

  __shared__ __align__(16) bf16_t Asm[128][32];  // 64B rows: conflict-free + lds-dma friendly
  __shared__ __align__(16) bf16_t Bsm[128][32];

  const int tid = threadIdx.x;
  const int lane = tid & 63;
  const int wave = tid >> 6;
  const int wm = wave & 1, wn = wave >> 1;
  const int quad = lane >> 4;
  const int l15 = lane & 15;

  // staging: thread -> (row = tid>>2, 16B chunk = tid&3); two issues cover 128 rows
  const int srow = tid >> 2;
  const int sch = tid & 3;
  int ai0 = tile0 + srow;       if (ai0 >= cnt) ai0 = cnt - 1;
  int ai1 = tile0 + 64 + srow;  if (ai1 >= cnt) ai1 = cnt - 1;
  const bf16_t* a_src0 = src + (size_t)rd[ai0].y * H_ + sch * 8;
  const bf16_t* a_src1 = src + (size_t)rd[ai1].y * H_ + sch * 8;
  const bf16_t* wsrc = Wt + ((size_t)t * 256 + nblk * 128) * 1280;
  const bf16_t* b_src0 = wsrc + (size_t)srow * 1280 + sch * 8;
  const bf16_t* b_src1 = wsrc + (size_t)(64 + srow) * 1280 + sch * 8;

  bf16_t* lds_a = &Asm[0][0] + wave * 512;  // bytes: wave*1024
  bf16_t* lds_b = &Bsm[0][0] + wave * 512;

  f32x4 acc[4][4];
#pragma unroll
  for (int i = 0; i < 4; ++i)
#pragma unroll
    for (int j = 0; j < 4; ++j) acc[i][j] = (f32x4){0.f, 0.f, 0.f, 0.f};

  for (int ks = 0; ks < 40; ++ks) {
    const int ko = ks * 32;
    gl2lds16(a_src0 + ko, lds_a);
    gl2lds16(a_src1 + ko, lds_a + 2048);
    gl2lds16(b_src0 + ko, lds_b);
    gl2lds16(b_src1 + ko, lds_b + 2048);
    __syncthreads();
    bf16x8 af[4], bfr[4];
#pragma unroll
    for (int am = 0; am < 4; ++am)
      af[am] = *(const bf16x8*)(&Asm[wm * 64 + am * 16 + l15][quad * 8]);
#pragma unroll
    for (int bn = 0; bn < 4; ++bn)
      bfr[bn] = *(const bf16x8*)(&Bsm[wn * 64 + bn * 16 + l15][quad * 8]);
#pragma unroll
    for (int am = 0; am < 4; ++am)
#pragma unroll
      for (int bn = 0; bn < 4; ++bn)
        acc[am][bn] = __builtin_amdgcn_mfma_f32_16x16x32_bf16(af[am], bfr[bn], acc[am][bn], 0, 0, 0);
    __syncthreads();
  }

  // Epilogue. C/D: col = l15 (n), row = quad*4 + reg (m).
  float wbv[4][6];
#pragma unroll
  for (int bn = 0; bn < 4; ++bn) {
    int col = nblk * 128 + wn * 64 + bn * 16 + l15;
    wbv[bn][0] = W_box[col];
    wbv[bn][1] = W_box[H_ + col];
    wbv[bn][2] = W_box[2 * H_ + col];
    wbv[bn][3] = W_box[3 * H_ + col];
    wbv[bn][4] = b_box[col];
    wbv[bn][5] = b_node[t * H_ + col];
  }
#pragma unroll
  for (int am = 0; am < 4; ++am) {
    int orow[4]; float4 bxv[4]; bool valid[4];
#pragma unroll
    for (int r = 0; r < 4; ++r) {
      int gidx = tile0 + wm * 64 + am * 16 + quad * 4 + r;
      valid[r] = (gidx < cnt);
      int ic = valid[r] ? gidx : (cnt - 1);
      int orw = rd[ic].x;
      orow[r] = orw;
      int b = orw / n_l;
      int i = orw - b * n_l;
      bxv[r] = *(const float4*)(ibox + ((size_t)b * NINT + off_l + i) * 4);
    }
#pragma unroll
    for (int bn = 0; bn < 4; ++bn) {
      int col = nblk * 128 + wn * 64 + bn * 16 + l15;
#pragma unroll
      for (int r = 0; r < 4; ++r) {
        if (!valid[r]) continue;
        float y = fmaxf(acc[am][bn][r] + wbv[bn][5], 0.f);
        float be = fmaf(wbv[bn][0], bxv[r].x,
                   fmaf(wbv[bn][1], bxv[r].y,
                   fmaf(wbv[bn][2], bxv[r].z,
                   fmaf(wbv[bn][3], bxv[r].w, wbv[bn][4]))));
        be = fmaxf(be, 0.f);
        dst[(size_t)orow[r] * H_ + col] = (bf16_t)(y + be);
      }
    }
  }
}

__global__ __launch_bounds__(256) void head_kernel(
    const bf16_t* __restrict__ f0, const float* __restrict__ eps,
    const float* __restrict__ W1, const float* __restrict__ b1,
    const float* __restrict__ Wmu, const float* __restrict__ bmu,
    const float* __restrict__ Wvar, const float* __restrict__ bvar,
    float* __restrict__ out) {
  __shared__ float root[256];
  __shared__ float enc[256];
  int b = blockIdx.x, h = threadIdx.x;
  root[h] = (float)f0[b * H_ + h];
  __syncthreads();
  float a = b1[h];
  for (int k = 0; k < 256; ++k) a = fmaf(root[k], W1[k * H_ + h], a);
  enc[h] = fmaxf(a, 0.f);
  __syncthreads();
  float m = bmu[h], lv = bvar[h];
  for (int k = 0; k < 256; ++k) {
    float e = enc[k];
    m = fmaf(e, Wmu[k * H_ + h], m);
    lv = fmaf(e, Wvar[k * H_ + h], lv);
  }
  float stdv = expf(0.5f * lv);
  float kld = 1.f + lv - m * m - expf(lv);
  out[b * 512 + h] = eps[b * H_ + h] * stdv + m;
  out[b * 512 + 256 + h] = kld;
}

extern "C" void kernel_launch(void* const* d_in, const int* in_sizes, int n_in,
                              void* d_out, int out_size, void* d_ws, size_t ws_size,
                              hipStream_t stream) {
  const float* leaf_box     = (const float*)d_in[0];
  const float* leaf_sem     = (const float*)d_in[1];
  const float* internal_box = (const float*)d_in[2];
  const int*   node_type    = (const int*)d_in[3];
  const float* eps          = (const float*)d_in[4];
  const float* W_box        = (const float*)d_in[5];
  const float* b_box        = (const float*)d_in[6];
  const float* W_sem        = (const float*)d_in[7];
  const float* b_sem        = (const float*)d_in[8];
  const float* W_node       = (const float*)d_in[9];
  const float* b_node       = (const float*)d_in[10];
  const float* W1           = (const float*)d_in[11];
  const float* b1           = (const float*)d_in[12];
  const float* Wmu          = (const float*)d_in[13];
  const float* bmu          = (const float*)d_in[14];
  const float* Wvar         = (const float*)d_in[15];
  const float* bvar         = (const float*)d_in[16];
  float* out = (float*)d_out;

  char* p = (char*)d_ws;
  auto alloc = [&](size_t bytes) {
    char* r = p;
    p += (bytes + 255) & ~(size_t)255;
    return r;
  };
  bf16_t* Wt = (bf16_t*)alloc((size_t)3 * 256 * 1280 * 2);
  const int n_tab[7] = {1, 5, 25, 125, 625, 3125, 15625};
  bf16_t* f[7];
  for (int l = 0; l <= 6; ++l) f[l] = (bf16_t*)alloc((size_t)B_ * n_tab[l] * H_ * 2);
  int* counters = (int*)alloc(18 * 4);
  int2* buckets = (int2*)alloc((size_t)187488 * 8);

  hipLaunchKernelGGL(prep_kernel, dim3(3840), dim3(256), 0, stream, W_node, Wt, counters);
  hipLaunchKernelGGL(leaf_kernel, dim3(4096), dim3(256), 0, stream,
                     leaf_box, leaf_sem, W_box, b_box, W_sem, b_sem, f[6]);
  hipLaunchKernelGGL(bucket_kernel, dim3((B_ * NINT + 255) / 256), dim3(256), 0, stream,
                     node_type, counters, buckets);

  const int lvl_base[6] = {0, 48, 288, 1488, 7488, 37488};
  const int off_tab[6]  = {0, 1, 6, 31, 156, 781};
  for (int l = 5; l >= 0; --l) {
    int cap = B_ * n_tab[l];
    int tiles = (cap + 127) / 128;
    hipLaunchKernelGGL(level_kernel, dim3(tiles, 3, 2), dim3(256), 0, stream,
                       f[l + 1], f[l], buckets + lvl_base[l], counters + l * 3,
                       Wt, b_node, internal_box, W_box, b_box,
                       n_tab[l], off_tab[l], cap);
  }
  hipLaunchKernelGGL(head_kernel, dim3(16), dim3(256), 0, stream,
                     f[0], eps, W1, b1, Wmu, bmu, Wvar, bvar, out);
}

// Round 3
// 433.057 us; speedup vs baseline: 1.8496x; 1.0045x over previous
//
#include <hip/hip_runtime.h>

// RecursiveEncoder on MI355X. B=16, H=256, S=16, C=5, L=6, N_LEAF=15625, N_INT=3906.
// R3: (1) leaf: 1 row/wave, 4h/lane, bf16x4 stores (was 2B scalar stores, 102us);
//     (2) level: LDS double-buffered lds-DMA prefetch + XOR chunk swizzle to kill
//         the 4-way b128 bank conflicts (4M conflict cycles in R2);
//     (3) prep: k-contiguous bf16x8 stores (was 2B scattered transpose writes).

#define B_ 16
#define H_ 256
#define NLEAF 15625
#define NINT 3906

typedef __bf16 bf16_t;
typedef bf16_t bf16x8 __attribute__((ext_vector_type(8)));
typedef bf16_t bf16x4 __attribute__((ext_vector_type(4)));
typedef float f32x4 __attribute__((ext_vector_type(4)));

__device__ __forceinline__ void gl2lds16(const bf16_t* g, bf16_t* l) {
  __builtin_amdgcn_global_load_lds((const __attribute__((address_space(1))) void*)g,
                                   (__attribute__((address_space(3))) void*)l,
                                   16, 0, 0);
}

// grid(24): t(3) x k-chunk(8 of 160). Reads coalesced (lane=h), writes 16B runs.
__global__ __launch_bounds__(256) void prep_kernel(const float* __restrict__ W_node,
                                                   bf16_t* __restrict__ Wt,
                                                   int* __restrict__ counters) {
  if (blockIdx.x == 0 && threadIdx.x < 18) counters[threadIdx.x] = 0;
  const int t = blockIdx.x / 8;
  const int kc = blockIdx.x % 8;
  const int h = threadIdx.x;
  const float* srcp = W_node + (size_t)t * 1280 * 256 + h;
  bf16_t* dstp = Wt + ((size_t)(t * 256 + h)) * 1280;
  for (int k0 = kc * 160; k0 < kc * 160 + 160; k0 += 8) {
    bf16x8 v;
#pragma unroll
    for (int j = 0; j < 8; ++j) v[j] = (bf16_t)srcp[(size_t)(k0 + j) * 256];
    *(bf16x8*)(dstp + k0) = v;
  }
}

// One row per wave, lane covers h = lane*4..lane*4+3; bf16x4 (8B) stores.
__global__ __launch_bounds__(256) void leaf_kernel(
    const float* __restrict__ leaf_box, const float* __restrict__ leaf_sem,
    const float* __restrict__ W_box, const float* __restrict__ b_box,
    const float* __restrict__ W_sem, const float* __restrict__ b_sem,
    bf16_t* __restrict__ f6) {
  const int lane = threadIdx.x & 63;
  const int wave = threadIdx.x >> 6;
  const int h0 = lane * 4;
  float wb[4][4], ws[16][4], bb[4], bs[4];
#pragma unroll
  for (int j = 0; j < 4; ++j) {
    float4 v = *(const float4*)(W_box + j * H_ + h0);
    wb[j][0] = v.x; wb[j][1] = v.y; wb[j][2] = v.z; wb[j][3] = v.w;
  }
#pragma unroll
  for (int j = 0; j < 16; ++j) {
    float4 v = *(const float4*)(W_sem + j * H_ + h0);
    ws[j][0] = v.x; ws[j][1] = v.y; ws[j][2] = v.z; ws[j][3] = v.w;
  }
  {
    float4 v = *(const float4*)(b_box + h0);
    bb[0] = v.x; bb[1] = v.y; bb[2] = v.z; bb[3] = v.w;
    float4 u = *(const float4*)(b_sem + h0);
    bs[0] = u.x; bs[1] = u.y; bs[2] = u.z; bs[3] = u.w;
  }
  const int ROWS = B_ * NLEAF;
  const int stride = gridDim.x * 4;
  for (int row = blockIdx.x * 4 + wave; row < ROWS; row += stride) {
    float4 bx = *(const float4*)(leaf_box + (size_t)row * 4);
    const float4* sp = (const float4*)(leaf_sem + (size_t)row * 16);
    float4 sv0 = sp[0], sv1 = sp[1], sv2 = sp[2], sv3 = sp[3];
    bf16x4 o;
#pragma unroll
    for (int c = 0; c < 4; ++c) {
      float s1 = fmaf(wb[0][c], bx.x, fmaf(wb[1][c], bx.y,
                 fmaf(wb[2][c], bx.z, fmaf(wb[3][c], bx.w, bb[c]))));
      float s2 = bs[c];
      s2 = fmaf(ws[0][c], sv0.x, s2);  s2 = fmaf(ws[1][c], sv0.y, s2);
      s2 = fmaf(ws[2][c], sv0.z, s2);  s2 = fmaf(ws[3][c], sv0.w, s2);
      s2 = fmaf(ws[4][c], sv1.x, s2);  s2 = fmaf(ws[5][c], sv1.y, s2);
      s2 = fmaf(ws[6][c], sv1.z, s2);  s2 = fmaf(ws[7][c], sv1.w, s2);
      s2 = fmaf(ws[8][c], sv2.x, s2);  s2 = fmaf(ws[9][c], sv2.y, s2);
      s2 = fmaf(ws[10][c], sv2.z, s2); s2 = fmaf(ws[11][c], sv2.w, s2);
      s2 = fmaf(ws[12][c], sv3.x, s2); s2 = fmaf(ws[13][c], sv3.y, s2);
      s2 = fmaf(ws[14][c], sv3.z, s2); s2 = fmaf(ws[15][c], sv3.w, s2);
      o[c] = (bf16_t)(fmaxf(s1, 0.f) + fmaxf(s2, 0.f));
    }
    *(bf16x4*)(f6 + (size_t)row * H_ + h0) = o;
  }
}

// LDS-aggregated bucketing.
__global__ __launch_bounds__(256) void bucket_kernel(const int* __restrict__ node_type,
                                                     int* __restrict__ counters,
                                                     int2* __restrict__ buckets) {
  __shared__ int lcnt[18];
  __shared__ int lbase[18];
  const int tid = threadIdx.x;
  if (tid < 18) lcnt[tid] = 0;
  __syncthreads();

  int idx = blockIdx.x * 256 + tid;
  bool active = idx < B_ * NINT;
  int t = 0, key = 0, mypos = 0;
  int2 e;
  int base = 0, nl_cap = 0;
  if (active) {
    int b = idx / NINT;
    int j = idx - b * NINT;
    int l, off;
    if (j >= 781)      { l = 5; off = 781; }
    else if (j >= 156) { l = 4; off = 156; }
    else if (j >= 31)  { l = 3; off = 31; }
    else if (j >= 6)   { l = 2; off = 6; }
    else if (j >= 1)   { l = 1; off = 1; }
    else               { l = 0; off = 0; }
    const int n_tab[6]    = {1, 5, 25, 125, 625, 3125};
    const int nn_tab[6]   = {5, 25, 125, 625, 3125, 15625};
    const int base_tab[6] = {0, 48, 288, 1488, 7488, 37488};
    int n_l = n_tab[l], nn = nn_tab[l];
    t = node_type[idx];
    int i = j - off;
    e.x = b * n_l + i;
    e.y = b * nn + 5 * i;
    base = base_tab[l];
    nl_cap = B_ * n_l;
    key = l * 3 + t;
    mypos = atomicAdd(&lcnt[key], 1);
  }
  __syncthreads();
  if (tid < 18) {
    int c = lcnt[tid];
    lbase[tid] = c ? atomicAdd(&counters[tid], c) : 0;
  }
  __syncthreads();
  if (active) {
    buckets[base + t * nl_cap + lbase[key] + mypos] = e;
  }
}

// 128x128 tile, K=1280 in 40 steps of 32, double-buffered lds-DMA, XOR swizzle.
__global__ __launch_bounds__(256) void level_kernel(
    const bf16_t* __restrict__ src, bf16_t* __restrict__ dst,
    const int2* __restrict__ bucket, const int* __restrict__ counters,
    const bf16_t* __restrict__ Wt, const float* __restrict__ b_node,
    const float* __restrict__ ibox, const float* __restrict__ W_box,
    const float* __restrict__ b_box, int n_l, int off_l, int cap) {
  const int t = blockIdx.y;
  const int cnt = counters[t];
  const int tile0 = blockIdx.x * 128;
  if (tile0 >= cnt) return;
  const int nblk = blockIdx.z;
  const int2* rd = bucket + (size_t)t * cap;

  __shared__ __align__(16) bf16_t Asm[2][128][32];
  __shared__ __align__(16) bf16_t Bsm[2][128][32];

  const int tid = threadIdx.x;
  const int lane = tid & 63;
  const int wave = tid >> 6;
  const int wm = wave & 1, wn = wave >> 1;
  const int quad = lane >> 4;
  const int l15 = lane & 15;

  // staging: LDS slot (srow, sch) <- global chunk sch ^ ((srow>>1)&3)
  const int srow = tid >> 2;
  const int sch = tid & 3;
  const int gch = sch ^ ((srow >> 1) & 3);  // same for rows srow and srow+64
  int ai0 = tile0 + srow;       if (ai0 >= cnt) ai0 = cnt - 1;
  int ai1 = tile0 + 64 + srow;  if (ai1 >= cnt) ai1 = cnt - 1;
  const bf16_t* a_src0 = src + (size_t)rd[ai0].y * H_ + gch * 8;
  const bf16_t* a_src1 = src + (size_t)rd[ai1].y * H_ + gch * 8;
  const bf16_t* wsrc = Wt + ((size_t)t * 256 + nblk * 128) * 1280;
  const bf16_t* b_src0 = wsrc + (size_t)srow * 1280 + gch * 8;
  const bf16_t* b_src1 = wsrc + (size_t)(64 + srow) * 1280 + gch * 8;

  f32x4 acc[4][4];
#pragma unroll
  for (int i = 0; i < 4; ++i)
#pragma unroll
    for (int j = 0; j < 4; ++j) acc[i][j] = (f32x4){0.f, 0.f, 0.f, 0.f};

  // physical chunk for logical k-chunk `quad`: quad ^ ((row>>1)&3) = quad ^ ((l15>>1)&3)
  const int pc8 = (quad ^ ((l15 >> 1) & 3)) * 8;

#define STAGE(buf, ks)                                            \
  {                                                               \
    const int ko = (ks) * 32;                                     \
    bf16_t* la = &Asm[buf][0][0] + wave * 512;                    \
    bf16_t* lb = &Bsm[buf][0][0] + wave * 512;                    \
    gl2lds16(a_src0 + ko, la);                                    \
    gl2lds16(a_src1 + ko, la + 2048);                             \
    gl2lds16(b_src0 + ko, lb);                                    \
    gl2lds16(b_src1 + ko, lb + 2048);                             \
  }

#define COMPUTE(buf)                                                           \
  {                                                                            \
    bf16x8 af[4], bfr[4];                                                      \
    _Pragma("unroll") for (int am = 0; am < 4; ++am)                           \
        af[am] = *(const bf16x8*)(&Asm[buf][wm * 64 + am * 16 + l15][pc8]);    \
    _Pragma("unroll") for (int bn = 0; bn < 4; ++bn)                           \
        bfr[bn] = *(const bf16x8*)(&Bsm[buf][wn * 64 + bn * 16 + l15][pc8]);   \
    _Pragma("unroll") for (int am = 0; am < 4; ++am)                           \
        _Pragma("unroll") for (int bn = 0; bn < 4; ++bn)                       \
            acc[am][bn] = __builtin_amdgcn_mfma_f32_16x16x32_bf16(             \
                af[am], bfr[bn], acc[am][bn], 0, 0, 0);                        \
  }

  STAGE(0, 0)
  for (int ks = 0; ks < 40; ks += 2) {
    __syncthreads();          // drains DMA for buf0 (issued last iter / preamble)
    STAGE(1, ks + 1)          // prefetch overlaps compute on buf0
    COMPUTE(0)
    __syncthreads();          // drains DMA for buf1
    if (ks + 2 < 40) STAGE(0, ks + 2)
    COMPUTE(1)
  }
#undef STAGE
#undef COMPUTE

  // Epilogue. C/D: col = l15 (n), row = quad*4 + reg (m).
  float wbv[4][6];
#pragma unroll
  for (int bn = 0; bn < 4; ++bn) {
    int col = nblk * 128 + wn * 64 + bn * 16 + l15;
    wbv[bn][0] = W_box[col];
    wbv[bn][1] = W_box[H_ + col];
    wbv[bn][2] = W_box[2 * H_ + col];
    wbv[bn][3] = W_box[3 * H_ + col];
    wbv[bn][4] = b_box[col];
    wbv[bn][5] = b_node[t * H_ + col];
  }
#pragma unroll
  for (int am = 0; am < 4; ++am) {
    int orow[4]; float4 bxv[4]; bool valid[4];
#pragma unroll
    for (int r = 0; r < 4; ++r) {
      int gidx = tile0 + wm * 64 + am * 16 + quad * 4 + r;
      valid[r] = (gidx < cnt);
      int ic = valid[r] ? gidx : (cnt - 1);
      int orw = rd[ic].x;
      orow[r] = orw;
      int b = orw / n_l;
      int i = orw - b * n_l;
      bxv[r] = *(const float4*)(ibox + ((size_t)b * NINT + off_l + i) * 4);
    }
#pragma unroll
    for (int bn = 0; bn < 4; ++bn) {
      int col = nblk * 128 + wn * 64 + bn * 16 + l15;
#pragma unroll
      for (int r = 0; r < 4; ++r) {
        if (!valid[r]) continue;
        float y = fmaxf(acc[am][bn][r] + wbv[bn][5], 0.f);
        float be = fmaf(wbv[bn][0], bxv[r].x,
                   fmaf(wbv[bn][1], bxv[r].y,
                   fmaf(wbv[bn][2], bxv[r].z,
                   fmaf(wbv[bn][3], bxv[r].w, wbv[bn][4]))));
        be = fmaxf(be, 0.f);
        dst[(size_t)orow[r] * H_ + col] = (bf16_t)(y + be);
      }
    }
  }
}

__global__ __launch_bounds__(256) void head_kernel(
    const bf16_t* __restrict__ f0, const float* __restrict__ eps,
    const float* __restrict__ W1, const float* __restrict__ b1,
    const float* __restrict__ Wmu, const float* __restrict__ bmu,
    const float* __restrict__ Wvar, const float* __restrict__ bvar,
    float* __restrict__ out) {
  __shared__ float root[256];
  __shared__ float enc[256];
  int b = blockIdx.x, h = threadIdx.x;
  root[h] = (float)f0[b * H_ + h];
  __syncthreads();
  float a = b1[h];
  for (int k = 0; k < 256; ++k) a = fmaf(root[k], W1[k * H_ + h], a);
  enc[h] = fmaxf(a, 0.f);
  __syncthreads();
  float m = bmu[h], lv = bvar[h];
  for (int k = 0; k < 256; ++k) {
    float e = enc[k];
    m = fmaf(e, Wmu[k * H_ + h], m);
    lv = fmaf(e, Wvar[k * H_ + h], lv);
  }
  float stdv = expf(0.5f * lv);
  float kld = 1.f + lv - m * m - expf(lv);
  out[b * 512 + h] = eps[b * H_ + h] * stdv + m;
  out[b * 512 + 256 + h] = kld;
}

extern "C" void kernel_launch(void* const* d_in, const int* in_sizes, int n_in,
                              void* d_out, int out_size, void* d_ws, size_t ws_size,
                              hipStream_t stream) {
  const float* leaf_box     = (const float*)d_in[0];
  const float* leaf_sem     = (const float*)d_in[1];
  const float* internal_box = (const float*)d_in[2];
  const int*   node_type    = (const int*)d_in[3];
  const float* eps          = (const float*)d_in[4];
  const float* W_box        = (const float*)d_in[5];
  const float* b_box        = (const float*)d_in[6];
  const float* W_sem        = (const float*)d_in[7];
  const float* b_sem        = (const float*)d_in[8];
  const float* W_node       = (const float*)d_in[9];
  const float* b_node       = (const float*)d_in[10];
  const float* W1           = (const float*)d_in[11];
  const float* b1           = (const float*)d_in[12];
  const float* Wmu          = (const float*)d_in[13];
  const float* bmu          = (const float*)d_in[14];
  const float* Wvar         = (const float*)d_in[15];
  const float* bvar         = (const float*)d_in[16];
  float* out = (float*)d_out;

  char* p = (char*)d_ws;
  auto alloc = [&](size_t bytes) {
    char* r = p;
    p += (bytes + 255) & ~(size_t)255;
    return r;
  };
  bf16_t* Wt = (bf16_t*)alloc((size_t)3 * 256 * 1280 * 2);
  const int n_tab[7] = {1, 5, 25, 125, 625, 3125, 15625};
  bf16_t* f[7];
  for (int l = 0; l <= 6; ++l) f[l] = (bf16_t*)alloc((size_t)B_ * n_tab[l] * H_ * 2);
  int* counters = (int*)alloc(18 * 4);
  int2* buckets = (int2*)alloc((size_t)187488 * 8);

  hipLaunchKernelGGL(prep_kernel, dim3(24), dim3(256), 0, stream, W_node, Wt, counters);
  hipLaunchKernelGGL(leaf_kernel, dim3(2048), dim3(256), 0, stream,
                     leaf_box, leaf_sem, W_box, b_box, W_sem, b_sem, f[6]);
  hipLaunchKernelGGL(bucket_kernel, dim3((B_ * NINT + 255) / 256), dim3(256), 0, stream,
                     node_type, counters, buckets);

  const int lvl_base[6] = {0, 48, 288, 1488, 7488, 37488};
  const int off_tab[6]  = {0, 1, 6, 31, 156, 781};
  for (int l = 5; l >= 0; --l) {
    int cap = B_ * n_tab[l];
    int tiles = (cap + 127) / 128;
    hipLaunchKernelGGL(level_kernel, dim3(tiles, 3, 2), dim3(256), 0, stream,
                       f[l + 1], f[l], buckets + lvl_base[l], counters + l * 3,
                       Wt, b_node, internal_box, W_box, b_box,
                       n_tab[l], off_tab[l], cap);
  }
  hipLaunchKernelGGL(head_kernel, dim3(16), dim3(256), 0, stream,
                     f[0], eps, W1, b1, Wmu, bmu, Wvar, bvar, out);
}